// Round 17
// baseline (998.731 us; speedup 1.0000x reference)
//
#include <hip/hip_runtime.h>

typedef unsigned short u16;
typedef short short8 __attribute__((ext_vector_type(8)));
typedef unsigned short u16x8 __attribute__((ext_vector_type(8)));
typedef float f32x4 __attribute__((ext_vector_type(4)));
typedef const __attribute__((address_space(1))) void* gptr_t;
typedef __attribute__((address_space(3))) void* lptr_t;

#define B_  64
#define S_  512
#define D_  1024
#define BS_ (B_*S_)

__device__ __forceinline__ float b2f(u16 v) {
    union { float f; unsigned u; } c; c.u = ((unsigned)v) << 16; return c.f;
}
__device__ __forceinline__ u16 f2b(float f) {
    union { float f; unsigned u; } c; c.f = f;
    unsigned r = c.u + 0x7FFFu + ((c.u >> 16) & 1u);
    return (u16)(r >> 16);
}

// ---------------- dtype flavor detector ----------------
__global__ void detect_k(const u16* __restrict__ raw, int* __restrict__ flag) {
    __shared__ int cnt;
    if (threadIdx.x == 0) cnt = 0;
    __syncthreads();
    u16 v = raw[threadIdx.x * 2];
    int e = (v >> 7) & 0xFF;
    int sane = (e >= 64 && e <= 150) ? 1 : 0;
    atomicAdd(&cnt, sane);
    __syncthreads();
    if (threadIdx.x == 0) *flag = (cnt >= 192) ? 1 : 0;   // 1 = bf16 inputs
}

// ---------------- convert 1-D params (biases, ln, lin) to bf16 ----------------
__global__ __launch_bounds__(256) void convert_params_k(
    const void* b0, const void* b1, const void* b2, const void* b3,
    const void* b4, const void* b5, const void* b6, const void* b7,
    const void* g, const void* be, const void* lw, const void* lb,
    const int* __restrict__ flagp, u16* __restrict__ dst)
{
    const void* srcs[12] = {b0, b1, b2, b3, b4, b5, b6, b7, g, be, lw, lb};
    int slot = blockIdx.x;
    int n = (slot == 11) ? 1 : 1024;
    int f = *flagp;
    const void* s = srcs[slot];
    for (int i = threadIdx.x; i < n; i += 256) {
        float v = f ? b2f(((const u16*)s)[i]) : ((const float*)s)[i];
        dst[slot * 1024 + i] = f2b(v);
    }
}

// ---------------- weight transpose+convert, ALL 8 weights in one dispatch ----------------
__global__ __launch_bounds__(256) void transpose_all_k(
    const void* w0, const void* w1, const void* w2, const void* w3,
    const void* w4, const void* w5, const void* w6, const void* w7,
    u16* __restrict__ WtBase, const int* __restrict__ flagp) {
    __shared__ float t[32][33];
    const void* srcs[8] = {w0, w1, w2, w3, w4, w5, w6, w7};
    int z = blockIdx.z;
    const void* W = srcs[z];
    u16* Wt = WtBase + (size_t)z * (D_ * D_);
    int f = *flagp;
    int tx = threadIdx.x, ty = threadIdx.y;
    int x0 = blockIdx.x * 32, y0 = blockIdx.y * 32;
    for (int i = ty; i < 32; i += 8) {
        size_t idx = (size_t)(y0 + i) * D_ + x0 + tx;
        t[i][tx] = f ? b2f(((const u16*)W)[idx]) : ((const float*)W)[idx];
    }
    __syncthreads();
    for (int i = ty; i < 32; i += 8)
        Wt[(size_t)(x0 + i) * D_ + y0 + tx] = f2b(t[tx][i]);
}

// ---------------- embedding: h0 = emb_w[x] + pos_w[s] ----------------
__global__ __launch_bounds__(256) void embed_k(const int* __restrict__ x, const void* __restrict__ emb,
                                               const void* __restrict__ pos, u16* __restrict__ h0,
                                               const int* __restrict__ flagp) {
    int f = *flagp;
    int bs = blockIdx.x;
    int s = bs & (S_ - 1);
    int tok = x[bs];
    u16* orow = h0 + (size_t)bs * D_;
    int c = threadIdx.x * 4;
    float e0, e1, e2, e3, p0, p1, p2, p3;
    if (f) {
        ushort4 e = *(const ushort4*)((const u16*)emb + (size_t)tok * D_ + c);
        ushort4 p = *(const ushort4*)((const u16*)pos + (size_t)s * D_ + c);
        e0 = b2f(e.x); e1 = b2f(e.y); e2 = b2f(e.z); e3 = b2f(e.w);
        p0 = b2f(p.x); p1 = b2f(p.y); p2 = b2f(p.z); p3 = b2f(p.w);
    } else {
        float4 e = *(const float4*)((const float*)emb + (size_t)tok * D_ + c);
        float4 p = *(const float4*)((const float*)pos + (size_t)s * D_ + c);
        e0 = e.x; e1 = e.y; e2 = e.z; e3 = e.w;
        p0 = p.x; p1 = p.y; p2 = p.z; p3 = p.w;
    }
    ushort4 o;
    o.x = f2b(e0 + p0); o.y = f2b(e1 + p1); o.z = f2b(e2 + p2); o.w = f2b(e3 + p3);
    *(ushort4*)(orow + c) = o;
}

// ====== QKV GEMM R17: 128x256 tile, BK=32, 48KB LDS -> 2 blocks/CU ======
// All six 256^2 schedule variants (1 block/CU) pinned at 245us; occupancy is
// the never-tested variable and the only lever that ever paid this session.
// 8 waves (2M x 4N), per-wave out 64x64 (acc[4][4]=64 VGPR; total ~120 <=128
// for launch_bounds(512,4) -> 16 waves/CU). BK=32 swizzle maps carried from
// R8 (measured 0 conflicts): write side pre-swizzled global k-slot
// (tid&3)^((tid>>3)&3), read side quad^((l16>>1)&3). ONE barrier per kt:
// barrier at iter-s top seals all waves' compute(s-1) ds_reads (retired at
// their lgkmcnt) before any wave issues STAGE(s+1) into buf (s-1)&1.
__global__ __launch_bounds__(512, 4) void gemmqkv_k(
    const u16* __restrict__ A, const u16* __restrict__ Bt,
    const u16* __restrict__ bias,
    u16* __restrict__ Cq, u16* __restrict__ Ck, u16* __restrict__ Vt)
{
    int bid = blockIdx.x;                 // 3072 blocks
    int xcd = bid & 7;
    int loc = bid >> 3;                   // 0..383 per XCD
    int chunk = loc >> 7;                 // 0..2 (4-n-tile chunks)
    int r = loc & 127;
    int mt = xcd * 32 + (r >> 2);         // 0..255 (128-row m-tiles)
    int nt = chunk * 4 + (r & 3);         // 0..11  (256-col n-tiles)
    int m0 = mt * 128, n0 = nt * 256;

    int tid = threadIdx.x;
    int lane = tid & 63, wid = tid >> 6, quad = lane >> 4, l16 = lane & 15;
    int wm = wid >> 2, wn = wid & 3;      // 2 x 4 wave grid; per-wave out 64x64
    int pxor = (l16 >> 1) & 3;            // read-side slot XOR ((row>>1)&3)

    // [buf][ A 128x32 | B 256x32 ] = 24 KB/buf, 48 KB total
    __shared__ __align__(16) u16 lds[2][12288];

    f32x4 acc[4][4];
#pragma unroll
    for (int i = 0; i < 4; i++)
#pragma unroll
        for (int j = 0; j < 4; j++) acc[i][j] = (f32x4){0.f, 0.f, 0.f, 0.f};

    int srow = tid >> 2;                                  // staging row (l=0)
    int skof = (((tid & 3) ^ ((tid >> 3) & 3)) * 8);      // pre-swizzled k off

    auto STAGE = [&](int s) {
        int p = s & 1;
        int kbase = s * 32;
        // A: one 16B inst covers 128x32
        __builtin_amdgcn_global_load_lds(
            (gptr_t)(A + (size_t)(m0 + srow) * D_ + kbase + skof),
            (lptr_t)(&lds[p][0] + tid * 8), 16, 0, 0);
        // B: two insts cover 256x32
#pragma unroll
        for (int l = 0; l < 2; ++l) {
            int row = l * 128 + srow;
            __builtin_amdgcn_global_load_lds(
                (gptr_t)(Bt + (size_t)(n0 + row) * D_ + kbase + skof),
                (lptr_t)(&lds[p][4096] + l * 4096 + tid * 8), 16, 0, 0);
        }
    };

    STAGE(0);
    for (int s = 0; s < 32; ++s) {
        int p = s & 1;
        asm volatile("s_waitcnt vmcnt(0)" ::: "memory");   // STAGE(s) retired
        __builtin_amdgcn_s_barrier();                      // visible + prev reads sealed
        const u16* Ah = &lds[p][0];
        const u16* Bh = &lds[p][4096];
        short8 af[4], bf[4];
#pragma unroll
        for (int mi = 0; mi < 4; ++mi)
            af[mi] = *(const short8*)&Ah[(wm * 64 + mi * 16 + l16) * 32 + ((quad ^ pxor) * 8)];
#pragma unroll
        for (int nj = 0; nj < 4; ++nj)
            bf[nj] = *(const short8*)&Bh[(wn * 64 + nj * 16 + l16) * 32 + ((quad ^ pxor) * 8)];
        if (s + 1 < 32) STAGE(s + 1);                      // into buf (s-1)&1: sealed above
        asm volatile("s_waitcnt lgkmcnt(0)" ::: "memory");
        __builtin_amdgcn_sched_barrier(0);                 // rule 18
        __builtin_amdgcn_s_setprio(1);
#pragma unroll
        for (int mi = 0; mi < 4; ++mi)
#pragma unroll
            for (int nj = 0; nj < 4; ++nj)
                acc[mi][nj] = __builtin_amdgcn_mfma_f32_16x16x32_bf16(
                    af[mi], bf[nj], acc[mi][nj], 0, 0, 0);
        __builtin_amdgcn_s_setprio(0);
    }

    // ---------- vectorized epilogue: per-wave LDS bounce, pitch-17 ----------
    __syncthreads();   // buffers dead; wave-private from here
    float* fl = (float*)(&lds[0][0]) + wid * 1104;   // 64 cols x pitch17 f32/wave

    int nbase = n0 + wn * 64;
    int rowb0 = m0 + wm * 64;
    bool vwave = (nbase >= 2048);

    if (vwave) {
        int colv = nbase + lane - 2048;
        float bv = b2f(bias[nbase + lane]);
#pragma unroll
        for (int mi = 0; mi < 4; ++mi) {
#pragma unroll
            for (int nj = 0; nj < 4; ++nj)
                *(f32x4*)&fl[(nj * 16 + l16) * 17 + quad * 4] = acc[mi][nj];
            asm volatile("s_waitcnt lgkmcnt(0)" ::: "memory");
            int rowbase = rowb0 + mi * 16;
            int bb = rowbase >> 9, sb0 = rowbase & (S_ - 1);
            u16x8 o0, o1;
#pragma unroll
            for (int s = 0; s < 8; ++s) {
                o0[s] = f2b(fl[lane * 17 + s] + bv);
                o1[s] = f2b(fl[lane * 17 + 8 + s] + bv);
            }
            u16* dst = Vt + ((size_t)bb * D_ + colv) * S_ + sb0;
            *(u16x8*)dst = o0;
            *(u16x8*)(dst + 8) = o1;
            asm volatile("" ::: "memory");
        }
    } else {
        u16* Cd = (nbase >= 1024) ? Ck : Cq;
        int rr2 = lane >> 2, sg = lane & 3;
        float bvv[2][8];
#pragma unroll
        for (int g = 0; g < 2; ++g) {
            u16x8 b8 = *(const u16x8*)&bias[nbase + sg * 8 + g * 32];
#pragma unroll
            for (int j = 0; j < 8; ++j) bvv[g][j] = b2f(b8[j]);
        }
#pragma unroll
        for (int mi = 0; mi < 4; ++mi) {
#pragma unroll
            for (int nj = 0; nj < 4; ++nj)
                *(f32x4*)&fl[(nj * 16 + l16) * 17 + quad * 4] = acc[mi][nj];
            asm volatile("s_waitcnt lgkmcnt(0)" ::: "memory");
            int row_g = rowb0 + mi * 16 + rr2;
#pragma unroll
            for (int g = 0; g < 2; ++g) {
                int c0 = sg * 8 + g * 32;
                int colc = (nbase + c0) & 1023;
                size_t idx = (size_t)row_g * D_ + colc;
                u16x8 o;
#pragma unroll
                for (int j = 0; j < 8; ++j)
                    o[j] = f2b(fl[(c0 + j) * 17 + rr2] + bvv[g][j]);
                *(u16x8*)&Cd[idx] = o;
            }
            asm volatile("" ::: "memory");
        }
    }
}

// ====== GEMM (R10 core): 256x256 -- kept for proj (NT=4) incl. fused pool ======
template <int NT>
__global__ __launch_bounds__(512, 2) void gemm256_k(
    const u16* __restrict__ A, const u16* __restrict__ Bt,
    const u16* __restrict__ bias,
    const u16* __restrict__ res, const u16* __restrict__ res2,
    u16* __restrict__ Cq, u16* __restrict__ Ck, u16* __restrict__ Vt,
    const int* __restrict__ xm, float* __restrict__ pool)
{
    int bid = blockIdx.x;
    int xcd = bid & 7;
    int loc = bid >> 3;
    int chunk = loc >> 6;
    int r = loc & 63;
    int mt = xcd * 16 + (r >> 2);
    int nt = chunk * 4 + (r & 3);
    int m0 = mt * 256, n0 = nt * 256;

    int tid = threadIdx.x;
    int lane = tid & 63, wid = tid >> 6, quad = lane >> 4, l16 = lane & 15;
    int wm = wid >> 2, wn = wid & 3;
    int pxor = l16 & 7;

    __shared__ __align__(16) u16 lds[2][2][2][128 * 64];

    f32x4 acc[8][4];
#pragma unroll
    for (int i = 0; i < 8; i++)
#pragma unroll
        for (int j = 0; j < 4; j++) acc[i][j] = (f32x4){0.f, 0.f, 0.f, 0.f};

    int srow = tid >> 3;
    int skof = ((tid & 7) ^ (srow & 7)) * 8;

    auto STAGE_HALF = [&](int kt, int mat, int hlf) {
        int p = kt & 1;
        int kbase = kt * 64;
        const u16* src = (mat == 0)
            ? A  + (size_t)(m0 + hlf * 128) * D_ + kbase
            : Bt + (size_t)(n0 + hlf * 128) * D_ + kbase;
        u16* dst = &lds[p][mat][hlf][0];
        __builtin_amdgcn_global_load_lds((gptr_t)(src + (size_t)srow * D_ + skof),
                                         (lptr_t)(dst + tid * 8), 16, 0, 0);
        __builtin_amdgcn_global_load_lds((gptr_t)(src + (size_t)(srow + 64) * D_ + skof),
                                         (lptr_t)(dst + 4096 + tid * 8), 16, 0, 0);
    };

    STAGE_HALF(0, 0, 0); STAGE_HALF(0, 0, 1);
    STAGE_HALF(0, 1, 0); STAGE_HALF(0, 1, 1);
    STAGE_HALF(1, 1, 0); STAGE_HALF(1, 1, 1);
    asm volatile("s_waitcnt vmcnt(4)" ::: "memory");
    __builtin_amdgcn_s_barrier();

    int brow0 = (wn & 1) * 64;
    for (int kt = 0; kt < 16; ++kt) {
        int p = kt & 1;
        const u16* Ah = &lds[p][0][wm][0];
        const u16* Bh = &lds[p][1][wn >> 1][0];
        short8 bf[4][2];
#pragma unroll
        for (int q = 0; q < 4; ++q) {
            if (q == 0) {
#pragma unroll
                for (int nj = 0; nj < 4; ++nj)
#pragma unroll
                    for (int kh = 0; kh < 2; ++kh)
                        bf[nj][kh] = *(const short8*)&Bh[(brow0 + nj * 16 + l16) * 64 +
                                                         ((kh * 4 + quad) ^ pxor) * 8];
            }
            short8 af[2][2];
#pragma unroll
            for (int mi2 = 0; mi2 < 2; ++mi2)
#pragma unroll
                for (int kh = 0; kh < 2; ++kh)
                    af[mi2][kh] = *(const short8*)&Ah[((2 * q + mi2) * 16 + l16) * 64 +
                                                      ((kh * 4 + quad) ^ pxor) * 8];
            if (q == 0 && kt + 1 < 16) STAGE_HALF(kt + 1, 0, 0);
            if (q == 1 && kt + 1 < 16) STAGE_HALF(kt + 1, 0, 1);
            if (q == 2 && kt + 2 < 16) STAGE_HALF(kt + 2, 1, 0);
            if (q == 3 && kt + 2 < 16) STAGE_HALF(kt + 2, 1, 1);
            __builtin_amdgcn_s_barrier();
            asm volatile("s_waitcnt lgkmcnt(0)" ::: "memory");
            __builtin_amdgcn_sched_barrier(0);
            __builtin_amdgcn_s_setprio(1);
#pragma unroll
            for (int kh = 0; kh < 2; ++kh)
#pragma unroll
                for (int mi2 = 0; mi2 < 2; ++mi2)
#pragma unroll
                    for (int nj = 0; nj < 4; ++nj)
                        acc[2 * q + mi2][nj] = __builtin_amdgcn_mfma_f32_16x16x32_bf16(
                            af[mi2][kh], bf[nj][kh], acc[2 * q + mi2][nj], 0, 0, 0);
            __builtin_amdgcn_s_setprio(0);
            __builtin_amdgcn_s_barrier();
        }
        if (kt < 15) {
            if (kt < 14) asm volatile("s_waitcnt vmcnt(4)" ::: "memory");
            else         asm volatile("s_waitcnt vmcnt(0)" ::: "memory");
            __builtin_amdgcn_s_barrier();
        }
    }

    __syncthreads();
    float* fl = (float*)(&lds[0][0][0][0]) + wid * 1104;

    int nbase = n0 + wn * 64;
    {
        u16* Cd = Cq;
        int rr2 = lane >> 2, sg = lane & 3;
        float bvv[2][8];
#pragma unroll
        for (int g = 0; g < 2; ++g) {
            u16x8 b8 = *(const u16x8*)&bias[nbase + sg * 8 + g * 32];
#pragma unroll
            for (int j = 0; j < 8; ++j) bvv[g][j] = b2f(b8[j]);
        }
        float psum[2][8];
#pragma unroll
        for (int g = 0; g < 2; ++g)
#pragma unroll
            for (int j = 0; j < 8; ++j) psum[g][j] = 0.f;
        int rowb0 = m0 + wm * 128;
        int b_ = rowb0 >> 9;
        const int* xb_ = pool ? (xm + b_ * S_) : nullptr;

#pragma unroll
        for (int mi = 0; mi < 8; ++mi) {
#pragma unroll
            for (int nj = 0; nj < 4; ++nj)
                *(f32x4*)&fl[(nj * 16 + l16) * 17 + quad * 4] = acc[mi][nj];
            asm volatile("s_waitcnt lgkmcnt(0)" ::: "memory");
            int row_g = rowb0 + mi * 16 + rr2;
            int msk = pool ? (xb_[row_g & (S_ - 1)] != 0) : 0;
#pragma unroll
            for (int g = 0; g < 2; ++g) {
                int c0 = sg * 8 + g * 32;
                int colc = (nbase + c0) & 1023;
                size_t idx = (size_t)row_g * D_ + colc;
                float v[8];
#pragma unroll
                for (int j = 0; j < 8; ++j)
                    v[j] = fl[(c0 + j) * 17 + rr2] + bvv[g][j];
                if (res) {
                    u16x8 r8 = *(const u16x8*)&res[idx];
#pragma unroll
                    for (int j = 0; j < 8; ++j) v[j] += b2f(r8[j]);
                }
                if (res2) {
                    u16x8 r8 = *(const u16x8*)&res2[idx];
#pragma unroll
                    for (int j = 0; j < 8; ++j) v[j] += b2f(r8[j]);
                }
                if (pool) {
                    if (msk)
#pragma unroll
                        for (int j = 0; j < 8; ++j) psum[g][j] += v[j];
                } else {
                    u16x8 o;
#pragma unroll
                    for (int j = 0; j < 8; ++j) o[j] = f2b(v[j]);
                    *(u16x8*)&Cd[idx] = o;
                }
            }
            asm volatile("" ::: "memory");
        }
        if (pool) {
#pragma unroll
            for (int g = 0; g < 2; ++g)
#pragma unroll
                for (int j = 0; j < 8; ++j) {
#pragma unroll
                    for (int m = 4; m <= 32; m <<= 1)
                        psum[g][j] += __shfl_xor(psum[g][j], m, 64);
                }
            if (rr2 == 0) {
#pragma unroll
                for (int g = 0; g < 2; ++g) {
                    int colc = (nbase + sg * 8 + g * 32) & 1023;
#pragma unroll
                    for (int j = 0; j < 8; ++j)
                        atomicAdd(&pool[b_ * 1024 + colc + j], psum[g][j]);
                }
            }
        }
    }
    (void)Ck; (void)Vt;
}

// ---------------- attention v8: NBUF=2 single-barrier for BOTH head dims ----------------
template <int HD, int NBUF>
__global__ __launch_bounds__(512, HD == 128 ? 4 : 2) void attn8_k(
    const u16* Q, const u16* __restrict__ Kn, const u16* __restrict__ Vt,
    const int* __restrict__ x, u16* O, int H)
{
    constexpr int NKF = HD / 32, NOF = HD / 16;
    constexpr int KP = HD + 8;
    constexpr int VP = (HD == 256 && NBUF == 2) ? 36 : 40;
    constexpr int KC = (32 * HD / 8) / 512;
    constexpr int VC = (HD * 32 / 8) / 512;
    const float scale = (HD == 128) ? 0.08838834764831845f : 0.0625f;
    int bh = blockIdx.x;
    int b = bh / H, h = bh - b * H;
    int tid = threadIdx.x, wid = tid >> 6, lane = tid & 63, quad = lane >> 4, l16 = lane & 15;
    int qrow = blockIdx.y * 128 + wid * 16;

    const u16* Qb = Q + (size_t)(b * S_) * D_ + h * HD;
    const u16* Kb = Kn + (size_t)(b * S_) * D_ + h * HD;
    const u16* Vb = Vt + ((size_t)b * D_ + h * HD) * S_;
    const int* xb = x + b * S_;

    __shared__ __align__(16) u16 Ks[NBUF][32 * KP];
    __shared__ __align__(16) u16 Vs[NBUF][HD * VP];
    __shared__ __align__(16) u16 Pl[8 * 16 * 32];

    short8 qf[NKF];
#pragma unroll
    for (int f = 0; f < NKF; ++f)
        qf[f] = *(const short8*)(Qb + (size_t)(qrow + l16) * D_ + f * 32 + quad * 8);

    f32x4 of[NOF];
    float lpart[4];
#pragma unroll
    for (int f = 0; f < NOF; ++f) of[f] = (f32x4){0.f, 0.f, 0.f, 0.f};
#pragma unroll
    for (int r = 0; r < 4; ++r) lpart[r] = 0.f;

    short8 kreg[KC], vreg[VC];
    auto LOADKV = [&](int key0) {
#pragma unroll
        for (int i = 0; i < KC; ++i) {
            int c = tid + i * 512;
            int row = c / (HD / 8), col = (c % (HD / 8)) * 8;
            kreg[i] = *(const short8*)(Kb + (size_t)(key0 + row) * D_ + col);
        }
#pragma unroll
        for (int i = 0; i < VC; ++i) {
            int c = tid + i * 512;
            int row = c >> 2, col = (c & 3) * 8;
            vreg[i] = *(const short8*)(Vb + (size_t)row * S_ + key0 + col);
        }
    };

    LOADKV(0);

    for (int t = 0; t < 16; ++t) {
        int key0 = t * 32;
        int p = (NBUF == 2) ? (t & 1) : 0;
        if (NBUF == 1) __syncthreads();
#pragma unroll
        for (int i = 0; i < KC; ++i) {
            int c = tid + i * 512;
            int row = c / (HD / 8), col = (c % (HD / 8)) * 8;
            *(short8*)&Ks[p][row * KP + col] = kreg[i];
        }
#pragma unroll
        for (int i = 0; i < VC; ++i) {
            int c = tid + i * 512;
            int row = c >> 2, col = (c & 3) * 8;
            *(short8*)&Vs[p][row * VP + col] = vreg[i];
        }
        if (key0 + 32 < S_) LOADKV(key0 + 32);
        int tok0 = xb[key0 + l16] != 0;
        int tok1 = xb[key0 + 16 + l16] != 0;
        __syncthreads();

        f32x4 sc0 = (f32x4){0.f, 0.f, 0.f, 0.f};
        f32x4 sc1 = (f32x4){0.f, 0.f, 0.f, 0.f};
#pragma unroll
        for (int f = 0; f < NKF; ++f) {
            short8 k0 = *(const short8*)&Ks[p][l16 * KP + f * 32 + quad * 8];
            short8 k1 = *(const short8*)&Ks[p][(16 + l16) * KP + f * 32 + quad * 8];
            sc0 = __builtin_amdgcn_mfma_f32_16x16x32_bf16(qf[f], k0, sc0, 0, 0, 0);
            sc1 = __builtin_amdgcn_mfma_f32_16x16x32_bf16(qf[f], k1, sc1, 0, 0, 0);
        }
#pragma unroll
        for (int r = 0; r < 4; ++r) {
            float p0 = tok0 ? __expf(sc0[r] * scale) : 0.f;
            float p1 = tok1 ? __expf(sc1[r] * scale) : 0.f;
            lpart[r] += p0 + p1;
            Pl[wid * 512 + (quad * 4 + r) * 32 + l16] = f2b(p0);
            Pl[wid * 512 + (quad * 4 + r) * 32 + 16 + l16] = f2b(p1);
        }
        __asm volatile("s_waitcnt lgkmcnt(0)" ::: "memory");
        short8 pf = *(const short8*)&Pl[wid * 512 + l16 * 32 + quad * 8];
#pragma unroll
        for (int f = 0; f < NOF; ++f) {
            short8 vf = *(const short8*)&Vs[p][(f * 16 + l16) * VP + quad * 8];
            of[f] = __builtin_amdgcn_mfma_f32_16x16x32_bf16(pf, vf, of[f], 0, 0, 0);
        }
    }

    u16* Ob = O + (size_t)(b * S_) * D_ + h * HD;
    float rl[4];
#pragma unroll
    for (int r = 0; r < 4; ++r) {
        float l = lpart[r];
#pragma unroll
        for (int msk = 1; msk < 16; msk <<= 1) l += __shfl_xor(l, msk, 64);
        rl[r] = 1.0f / l;
    }
#pragma unroll
    for (int f = 0; f < NOF; ++f)
#pragma unroll
        for (int r = 0; r < 4; ++r)
            Ob[(size_t)(qrow + quad * 4 + r) * D_ + f * 16 + l16] =
                f2b(of[f][r] * rl[r]);
}

// ---------------- pool stage 0: zero accumulators ----------------
__global__ __launch_bounds__(256) void pool_zero_k(float* __restrict__ pooled) {
    int b = blockIdx.x;
    for (int i = threadIdx.x; i < 1024; i += 256) pooled[b * 1024 + i] = 0.f;
}

// ---------------- pool final: count tokens inline + LayerNorm + linear ----------------
__global__ __launch_bounds__(256) void pool_final_k(
    const float* __restrict__ pooled, const int* __restrict__ x,
    const u16* __restrict__ prm, void* __restrict__ out, const int* __restrict__ flagp)
{
    __shared__ float sb[8];
    __shared__ int sbi[4];
    const u16* g  = prm + 8 * 1024;
    const u16* be = prm + 9 * 1024;
    const u16* lw = prm + 10 * 1024;
    const u16* lb = prm + 11 * 1024;
    int b = blockIdx.x;
    int c = threadIdx.x * 4;
    int wid = threadIdx.x >> 6, lane = threadIdx.x & 63;

    const int* xb = x + b * S_;
    int localc = 0;
    for (int i = threadIdx.x; i < S_; i += 256) localc += (xb[i] != 0);
#pragma unroll
    for (int m = 32; m >= 1; m >>= 1) localc += __shfl_xor(localc, m, 64);
    if (lane == 0) sbi[wid] = localc;
    __syncthreads();
    int n = sbi[0] + sbi[1] + sbi[2] + sbi[3];

    float inv = 1.0f / (float)(n > 0 ? n : 1);
    float p0 = pooled[b * 1024 + c + 0] * inv;
    float p1 = pooled[b * 1024 + c + 1] * inv;
    float p2 = pooled[b * 1024 + c + 2] * inv;
    float p3 = pooled[b * 1024 + c + 3] * inv;
    float s1 = p0 + p1 + p2 + p3;
    float s2 = p0 * p0 + p1 * p1 + p2 * p2 + p3 * p3;
#pragma unroll
    for (int m = 32; m >= 1; m >>= 1) { s1 += __shfl_xor(s1, m, 64); s2 += __shfl_xor(s2, m, 64); }
    if (lane == 0) { sb[wid] = s1; sb[4 + wid] = s2; }
    __syncthreads();
    float S1 = sb[0] + sb[1] + sb[2] + sb[3];
    float S2 = sb[4] + sb[5] + sb[6] + sb[7];
    float mu = S1 * (1.0f / 1024.0f);
    float var = S2 * (1.0f / 1024.0f) - mu * mu;
    float rstd = rsqrtf(var + 1e-5f);
    float dot = ((p0 - mu) * rstd * b2f(g[c + 0]) + b2f(be[c + 0])) * b2f(lw[c + 0])
              + ((p1 - mu) * rstd * b2f(g[c + 1]) + b2f(be[c + 1])) * b2f(lw[c + 1])
              + ((p2 - mu) * rstd * b2f(g[c + 2]) + b2f(be[c + 2])) * b2f(lw[c + 2])
              + ((p3 - mu) * rstd * b2f(g[c + 3]) + b2f(be[c + 3])) * b2f(lw[c + 3]);
#pragma unroll
    for (int m = 32; m >= 1; m >>= 1) dot += __shfl_xor(dot, m, 64);
    __syncthreads();
    if (lane == 0) sb[wid] = dot;
    __syncthreads();
    if (threadIdx.x == 0) {
        float v = sb[0] + sb[1] + sb[2] + sb[3] + b2f(lb[0]);
        if (*flagp) ((u16*)out)[b] = f2b(v);
        else        ((float*)out)[b] = v;
    }
}

extern "C" void kernel_launch(void* const* d_in, const int* in_sizes, int n_in,
                              void* d_out, int out_size, void* d_ws, size_t ws_size,
                              hipStream_t stream)
{
    (void)in_sizes; (void)n_in; (void)out_size; (void)ws_size;
    const int* x = (const int*)d_in[0];

    char* ws = (char*)d_ws;
    size_t off = 0;
    auto carve = [&](size_t bytes) -> char* {
        char* p = ws + off;
        off += (bytes + 255) & ~(size_t)255;
        return p;
    };
    int* flag    = (int*)carve(256);
    u16* prm     = (u16*)carve(12 * 1024 * 2);
    float* pooled = (float*)carve(64 * 1024 * 4);
    const size_t WB = (size_t)D_ * D_ * 2;   // 2 MiB
    const size_t HB = (size_t)BS_ * D_ * 2;  // 64 MiB
    u16* wt0 = (u16*)carve(WB * 8);          // 8 transposed weights, contiguous
    u16* h0   = (u16*)carve(HB);
    u16* buf2 = (u16*)carve(HB);
    u16* buf3 = (u16*)carve(HB);
    u16* buf4 = (u16*)carve(HB);
    u16* buf5 = (u16*)carve(HB);
    const size_t WE = (size_t)D_ * D_;       // elements per weight

    detect_k<<<1, 256, 0, stream>>>((const u16*)d_in[1], flag);
    convert_params_k<<<12, 256, 0, stream>>>(
        d_in[4], d_in[6], d_in[8], d_in[10], d_in[12], d_in[14], d_in[16], d_in[18],
        d_in[19], d_in[20], d_in[21], d_in[22], flag, prm);

    transpose_all_k<<<dim3(32, 32, 8), dim3(32, 8), 0, stream>>>(
        d_in[3], d_in[5], d_in[7], d_in[9], d_in[11], d_in[13], d_in[15], d_in[17],
        wt0, flag);

    embed_k<<<BS_, 256, 0, stream>>>(x, d_in[1], d_in[2], h0, flag);

    pool_zero_k<<<B_, 256, 0, stream>>>(pooled);

    // MHA1: fused QKV via the 2-blocks/CU 128x256 kernel
    gemmqkv_k<<<3072, 512, 0, stream>>>(h0, wt0 + 0 * WE, prm + 0 * 1024,
                                        buf2, buf3, buf4);
    attn8_k<128, 2><<<dim3(B_ * 8, 4), 512, 0, stream>>>(buf2, buf3, buf4, x, buf2, 8);
    gemm256_k<4><<<512, 512, 0, stream>>>(buf2, wt0 + 3 * WE, prm + 3 * 1024,
                                          h0, nullptr, buf5, nullptr, nullptr,
                                          nullptr, nullptr);
    // MHA2: fused QKV
    gemmqkv_k<<<3072, 512, 0, stream>>>(buf5, wt0 + 4 * WE, prm + 4 * 1024,
                                        buf2, buf3, buf4);
    attn8_k<256, 2><<<dim3(B_ * 4, 4), 512, 0, stream>>>(buf2, buf3, buf4, x, buf2, 4);
    // final proj: fuses residuals AND the masked mean-pool accumulation
    gemm256_k<4><<<512, 512, 0, stream>>>(buf2, wt0 + 7 * WE, prm + 7 * 1024,
                                          buf5, h0, nullptr, nullptr, nullptr,
                                          x, pooled);

    pool_final_k<<<B_, 256, 0, stream>>>(pooled, x, prm, d_out, flag);
}

// Round 18
// 976.286 us; speedup vs baseline: 1.0230x; 1.0230x over previous
//
#include <hip/hip_runtime.h>

typedef unsigned short u16;
typedef short short8 __attribute__((ext_vector_type(8)));
typedef unsigned short u16x8 __attribute__((ext_vector_type(8)));
typedef float f32x4 __attribute__((ext_vector_type(4)));
typedef const __attribute__((address_space(1))) void* gptr_t;
typedef __attribute__((address_space(3))) void* lptr_t;

#define B_  64
#define S_  512
#define D_  1024
#define BS_ (B_*S_)

__device__ __forceinline__ float b2f(u16 v) {
    union { float f; unsigned u; } c; c.u = ((unsigned)v) << 16; return c.f;
}
__device__ __forceinline__ u16 f2b(float f) {
    union { float f; unsigned u; } c; c.f = f;
    unsigned r = c.u + 0x7FFFu + ((c.u >> 16) & 1u);
    return (u16)(r >> 16);
}

// ---------------- dtype flavor detector ----------------
__global__ void detect_k(const u16* __restrict__ raw, int* __restrict__ flag) {
    __shared__ int cnt;
    if (threadIdx.x == 0) cnt = 0;
    __syncthreads();
    u16 v = raw[threadIdx.x * 2];
    int e = (v >> 7) & 0xFF;
    int sane = (e >= 64 && e <= 150) ? 1 : 0;
    atomicAdd(&cnt, sane);
    __syncthreads();
    if (threadIdx.x == 0) *flag = (cnt >= 192) ? 1 : 0;   // 1 = bf16 inputs
}

// ---------------- convert 1-D params (biases, ln, lin) to bf16 ----------------
__global__ __launch_bounds__(256) void convert_params_k(
    const void* b0, const void* b1, const void* b2, const void* b3,
    const void* b4, const void* b5, const void* b6, const void* b7,
    const void* g, const void* be, const void* lw, const void* lb,
    const int* __restrict__ flagp, u16* __restrict__ dst)
{
    const void* srcs[12] = {b0, b1, b2, b3, b4, b5, b6, b7, g, be, lw, lb};
    int slot = blockIdx.x;
    int n = (slot == 11) ? 1 : 1024;
    int f = *flagp;
    const void* s = srcs[slot];
    for (int i = threadIdx.x; i < n; i += 256) {
        float v = f ? b2f(((const u16*)s)[i]) : ((const float*)s)[i];
        dst[slot * 1024 + i] = f2b(v);
    }
}

// ---------------- weight transpose+convert, ALL 8 weights in one dispatch ----------------
__global__ __launch_bounds__(256) void transpose_all_k(
    const void* w0, const void* w1, const void* w2, const void* w3,
    const void* w4, const void* w5, const void* w6, const void* w7,
    u16* __restrict__ WtBase, const int* __restrict__ flagp) {
    __shared__ float t[32][33];
    const void* srcs[8] = {w0, w1, w2, w3, w4, w5, w6, w7};
    int z = blockIdx.z;
    const void* W = srcs[z];
    u16* Wt = WtBase + (size_t)z * (D_ * D_);
    int f = *flagp;
    int tx = threadIdx.x, ty = threadIdx.y;
    int x0 = blockIdx.x * 32, y0 = blockIdx.y * 32;
    for (int i = ty; i < 32; i += 8) {
        size_t idx = (size_t)(y0 + i) * D_ + x0 + tx;
        t[i][tx] = f ? b2f(((const u16*)W)[idx]) : ((const float*)W)[idx];
    }
    __syncthreads();
    for (int i = ty; i < 32; i += 8)
        Wt[(size_t)(x0 + i) * D_ + y0 + tx] = f2b(t[tx][i]);
}

// ---------------- embedding: h0 = emb_w[x] + pos_w[s] ----------------
__global__ __launch_bounds__(256) void embed_k(const int* __restrict__ x, const void* __restrict__ emb,
                                               const void* __restrict__ pos, u16* __restrict__ h0,
                                               const int* __restrict__ flagp) {
    int f = *flagp;
    int bs = blockIdx.x;
    int s = bs & (S_ - 1);
    int tok = x[bs];
    u16* orow = h0 + (size_t)bs * D_;
    int c = threadIdx.x * 4;
    float e0, e1, e2, e3, p0, p1, p2, p3;
    if (f) {
        ushort4 e = *(const ushort4*)((const u16*)emb + (size_t)tok * D_ + c);
        ushort4 p = *(const ushort4*)((const u16*)pos + (size_t)s * D_ + c);
        e0 = b2f(e.x); e1 = b2f(e.y); e2 = b2f(e.z); e3 = b2f(e.w);
        p0 = b2f(p.x); p1 = b2f(p.y); p2 = b2f(p.z); p3 = b2f(p.w);
    } else {
        float4 e = *(const float4*)((const float*)emb + (size_t)tok * D_ + c);
        float4 p = *(const float4*)((const float*)pos + (size_t)s * D_ + c);
        e0 = e.x; e1 = e.y; e2 = e.z; e3 = e.w;
        p0 = p.x; p1 = p.y; p2 = p.z; p3 = p.w;
    }
    ushort4 o;
    o.x = f2b(e0 + p0); o.y = f2b(e1 + p1); o.z = f2b(e2 + p2); o.w = f2b(e3 + p3);
    *(ushort4*)(orow + c) = o;
}

// ====== GEMM (R10 core): 256x256, 8-phase, counted vmcnt, vector epilogue ======
// Final-proj variant fuses the masked mean-pool accumulation into the epilogue
// (pool != nullptr): psum[2][8] per thread (8 rows share one batch idx),
// shfl-reduce over rr2 lane bits, rr2==0 lanes issue 16 atomicAdds.
// NOTE (R17 refutation): this kernel's 244-246us at this shape is invariant
// to schedule (6 variants) AND occupancy (2 blocks/CU variant, R17 null) --
// best-known configuration, iteration concluded.
template <int NT>   // n-tiles of 256: 12 (fused QKV, N=3072) or 4 (proj, N=1024)
__global__ __launch_bounds__(512, 2) void gemm256_k(
    const u16* __restrict__ A, const u16* __restrict__ Bt,
    const u16* __restrict__ bias,
    const u16* __restrict__ res, const u16* __restrict__ res2,
    u16* __restrict__ Cq, u16* __restrict__ Ck, u16* __restrict__ Vt,
    const int* __restrict__ xm, float* __restrict__ pool)
{
    int bid = blockIdx.x;
    int xcd = bid & 7;
    int loc = bid >> 3;                 // 0 .. 16*NT-1 per XCD
    int chunk = loc >> 6;               // 4-n-tile chunks (64 blocks each)
    int r = loc & 63;
    int mt = xcd * 16 + (r >> 2);       // 16-m-tile strip per XCD
    int nt = chunk * 4 + (r & 3);       // n innermost within chunk
    int m0 = mt * 256, n0 = nt * 256;

    int tid = threadIdx.x;
    int lane = tid & 63, wid = tid >> 6, quad = lane >> 4, l16 = lane & 15;
    int wm = wid >> 2, wn = wid & 3;    // 2 x 4 wave grid; per-wave out 128x64
    int pxor = l16 & 7;                 // read-side slot XOR (row&7 == l16&7)

    // [parity][matrix 0=A 1=B][half][128*64] bf16 = 128 KiB
    __shared__ __align__(16) u16 lds[2][2][2][128 * 64];

    f32x4 acc[8][4];
#pragma unroll
    for (int i = 0; i < 8; i++)
#pragma unroll
        for (int j = 0; j < 4; j++) acc[i][j] = (f32x4){0.f, 0.f, 0.f, 0.f};

    // staging map: inst l of half -> LDS linear byte l*8192 + tid*16
    int srow = tid >> 3;                       // l=0 row (l=1: srow+64, same row&7)
    int skof = ((tid & 7) ^ (srow & 7)) * 8;   // pre-swizzled k offset (u16)

    auto STAGE_HALF = [&](int kt, int mat, int hlf) {
        int p = kt & 1;
        int kbase = kt * 64;
        const u16* src = (mat == 0)
            ? A  + (size_t)(m0 + hlf * 128) * D_ + kbase
            : Bt + (size_t)(n0 + hlf * 128) * D_ + kbase;
        u16* dst = &lds[p][mat][hlf][0];
        __builtin_amdgcn_global_load_lds((gptr_t)(src + (size_t)srow * D_ + skof),
                                         (lptr_t)(dst + tid * 8), 16, 0, 0);
        __builtin_amdgcn_global_load_lds((gptr_t)(src + (size_t)(srow + 64) * D_ + skof),
                                         (lptr_t)(dst + 4096 + tid * 8), 16, 0, 0);
    };

    // prologue: kt0 all 4 halves + kt1's B halves
    STAGE_HALF(0, 0, 0); STAGE_HALF(0, 0, 1);
    STAGE_HALF(0, 1, 0); STAGE_HALF(0, 1, 1);
    STAGE_HALF(1, 1, 0); STAGE_HALF(1, 1, 1);
    asm volatile("s_waitcnt vmcnt(4)" ::: "memory");   // kt0's 4 halves retired
    __builtin_amdgcn_s_barrier();

    int brow0 = (wn & 1) * 64;              // B row base within B-half
    for (int kt = 0; kt < 16; ++kt) {
        int p = kt & 1;
        const u16* Ah = &lds[p][0][wm][0];
        const u16* Bh = &lds[p][1][wn >> 1][0];
        short8 bf[4][2];
#pragma unroll
        for (int q = 0; q < 4; ++q) {
            if (q == 0) {
#pragma unroll
                for (int nj = 0; nj < 4; ++nj)
#pragma unroll
                    for (int kh = 0; kh < 2; ++kh)
                        bf[nj][kh] = *(const short8*)&Bh[(brow0 + nj * 16 + l16) * 64 +
                                                         ((kh * 4 + quad) ^ pxor) * 8];
            }
            short8 af[2][2];
#pragma unroll
            for (int mi2 = 0; mi2 < 2; ++mi2)
#pragma unroll
                for (int kh = 0; kh < 2; ++kh)
                    af[mi2][kh] = *(const short8*)&Ah[((2 * q + mi2) * 16 + l16) * 64 +
                                                      ((kh * 4 + quad) ^ pxor) * 8];
            // staggered staging: one matrix-half per phase
            if (q == 0 && kt + 1 < 16) STAGE_HALF(kt + 1, 0, 0);
            if (q == 1 && kt + 1 < 16) STAGE_HALF(kt + 1, 0, 1);
            if (q == 2 && kt + 2 < 16) STAGE_HALF(kt + 2, 1, 0);
            if (q == 3 && kt + 2 < 16) STAGE_HALF(kt + 2, 1, 1);
            __builtin_amdgcn_s_barrier();                      // ds_read latency hides here
            asm volatile("s_waitcnt lgkmcnt(0)" ::: "memory"); // own frags resident
            __builtin_amdgcn_sched_barrier(0);                 // rule 18: pin MFMA after wait
            __builtin_amdgcn_s_setprio(1);
#pragma unroll
            for (int kh = 0; kh < 2; ++kh)
#pragma unroll
                for (int mi2 = 0; mi2 < 2; ++mi2)
#pragma unroll
                    for (int nj = 0; nj < 4; ++nj)
                        acc[2 * q + mi2][nj] = __builtin_amdgcn_mfma_f32_16x16x32_bf16(
                            af[mi2][kh], bf[nj][kh], acc[2 * q + mi2][nj], 0, 0, 0);
            __builtin_amdgcn_s_setprio(0);
            __builtin_amdgcn_s_barrier();
        }
        if (kt < 15) {
            if (kt < 14) asm volatile("s_waitcnt vmcnt(4)" ::: "memory");
            else         asm volatile("s_waitcnt vmcnt(0)" ::: "memory");
            __builtin_amdgcn_s_barrier();
        }
    }

    // ---------- vectorized epilogue: per-wave LDS bounce, pitch-17 ----------
    __syncthreads();   // dbuf dead; after this all LDS use is wave-private
    float* fl = (float*)(&lds[0][0][0][0]) + wid * 1104;   // 64 cols x pitch17 f32/wave

    int nbase = n0 + wn * 64;
    bool vwave = (NT == 12) && (nbase >= 2048);

    if (vwave) {
        int colv = nbase + lane - 2048;               // this lane's d-column
        float bv = b2f(bias[nbase + lane]);
#pragma unroll
        for (int mi = 0; mi < 8; ++mi) {
#pragma unroll
            for (int nj = 0; nj < 4; ++nj)
                *(f32x4*)&fl[(nj * 16 + l16) * 17 + quad * 4] = acc[mi][nj];
            asm volatile("s_waitcnt lgkmcnt(0)" ::: "memory");  // wave-private w->r
            int rowbase = m0 + wm * 128 + mi * 16;
            int bb = rowbase >> 9, sb0 = rowbase & (S_ - 1);
            u16x8 o0, o1;
#pragma unroll
            for (int s = 0; s < 8; ++s) {
                o0[s] = f2b(fl[lane * 17 + s] + bv);
                o1[s] = f2b(fl[lane * 17 + 8 + s] + bv);
            }
            u16* dst = Vt + ((size_t)bb * D_ + colv) * S_ + sb0;
            *(u16x8*)dst = o0;
            *(u16x8*)(dst + 8) = o1;
            asm volatile("" ::: "memory");             // pin read-before-next-write
        }
    } else {
        u16* Cd = (NT == 12 && nbase >= 1024) ? Ck : Cq;
        int rr2 = lane >> 2, sg = lane & 3;
        float bvv[2][8];
#pragma unroll
        for (int g = 0; g < 2; ++g) {
            u16x8 b8 = *(const u16x8*)&bias[nbase + sg * 8 + g * 32];
#pragma unroll
            for (int j = 0; j < 8; ++j) bvv[g][j] = b2f(b8[j]);
        }
        // fused-pool state (final proj only)
        float psum[2][8];
#pragma unroll
        for (int g = 0; g < 2; ++g)
#pragma unroll
            for (int j = 0; j < 8; ++j) psum[g][j] = 0.f;
        int rowb0 = m0 + wm * 128;
        int b_ = rowb0 >> 9;                          // all 8 rows share one batch
        const int* xb_ = pool ? (xm + b_ * S_) : nullptr;

#pragma unroll
        for (int mi = 0; mi < 8; ++mi) {
#pragma unroll
            for (int nj = 0; nj < 4; ++nj)
                *(f32x4*)&fl[(nj * 16 + l16) * 17 + quad * 4] = acc[mi][nj];
            asm volatile("s_waitcnt lgkmcnt(0)" ::: "memory");  // wave-private w->r
            int row_g = rowb0 + mi * 16 + rr2;
            int msk = pool ? (xb_[row_g & (S_ - 1)] != 0) : 0;
#pragma unroll
            for (int g = 0; g < 2; ++g) {
                int c0 = sg * 8 + g * 32;
                int colc = (nbase + c0) & 1023;
                size_t idx = (size_t)row_g * D_ + colc;
                float v[8];
#pragma unroll
                for (int j = 0; j < 8; ++j)
                    v[j] = fl[(c0 + j) * 17 + rr2] + bvv[g][j];
                if (res) {
                    u16x8 r8 = *(const u16x8*)&res[idx];
#pragma unroll
                    for (int j = 0; j < 8; ++j) v[j] += b2f(r8[j]);
                }
                if (res2) {
                    u16x8 r8 = *(const u16x8*)&res2[idx];
#pragma unroll
                    for (int j = 0; j < 8; ++j) v[j] += b2f(r8[j]);
                }
                if (pool) {
                    if (msk)
#pragma unroll
                        for (int j = 0; j < 8; ++j) psum[g][j] += v[j];
                } else {
                    u16x8 o;
#pragma unroll
                    for (int j = 0; j < 8; ++j) o[j] = f2b(v[j]);
                    *(u16x8*)&Cd[idx] = o;
                }
            }
            asm volatile("" ::: "memory");             // pin read-before-next-write
        }
        if (pool) {
            // reduce across the 16 lanes sharing (sg,g) -> lane bits 2..5 (rr2)
#pragma unroll
            for (int g = 0; g < 2; ++g)
#pragma unroll
                for (int j = 0; j < 8; ++j) {
#pragma unroll
                    for (int m = 4; m <= 32; m <<= 1)
                        psum[g][j] += __shfl_xor(psum[g][j], m, 64);
                }
            if (rr2 == 0) {
#pragma unroll
                for (int g = 0; g < 2; ++g) {
                    int colc = (nbase + sg * 8 + g * 32) & 1023;
#pragma unroll
                    for (int j = 0; j < 8; ++j)
                        atomicAdd(&pool[b_ * 1024 + colc + j], psum[g][j]);
                }
            }
        }
    }
}

// ---------------- attention v8: NBUF=2 single-barrier for BOTH head dims ----------------
template <int HD, int NBUF>
__global__ __launch_bounds__(512, HD == 128 ? 4 : 2) void attn8_k(
    const u16* Q, const u16* __restrict__ Kn, const u16* __restrict__ Vt,
    const int* __restrict__ x, u16* O, int H)
{
    constexpr int NKF = HD / 32, NOF = HD / 16;
    constexpr int KP = HD + 8;   // padded K-tile row
    constexpr int VP = (HD == 256 && NBUF == 2) ? 36 : 40;   // V-tile row pad
    constexpr int KC = (32 * HD / 8) / 512;   // K chunks per thread (1 or 2)
    constexpr int VC = (HD * 32 / 8) / 512;   // V chunks per thread (1 or 2)
    const float scale = (HD == 128) ? 0.08838834764831845f : 0.0625f;
    int bh = blockIdx.x;
    int b = bh / H, h = bh - b * H;
    int tid = threadIdx.x, wid = tid >> 6, lane = tid & 63, quad = lane >> 4, l16 = lane & 15;
    int qrow = blockIdx.y * 128 + wid * 16;

    const u16* Qb = Q + (size_t)(b * S_) * D_ + h * HD;
    const u16* Kb = Kn + (size_t)(b * S_) * D_ + h * HD;
    const u16* Vb = Vt + ((size_t)b * D_ + h * HD) * S_;
    const int* xb = x + b * S_;

    __shared__ __align__(16) u16 Ks[NBUF][32 * KP];
    __shared__ __align__(16) u16 Vs[NBUF][HD * VP];
    __shared__ __align__(16) u16 Pl[8 * 16 * 32];

    short8 qf[NKF];
#pragma unroll
    for (int f = 0; f < NKF; ++f)
        qf[f] = *(const short8*)(Qb + (size_t)(qrow + l16) * D_ + f * 32 + quad * 8);

    f32x4 of[NOF];
    float lpart[4];
#pragma unroll
    for (int f = 0; f < NOF; ++f) of[f] = (f32x4){0.f, 0.f, 0.f, 0.f};
#pragma unroll
    for (int r = 0; r < 4; ++r) lpart[r] = 0.f;

    short8 kreg[KC], vreg[VC];
    auto LOADKV = [&](int key0) {
#pragma unroll
        for (int i = 0; i < KC; ++i) {
            int c = tid + i * 512;
            int row = c / (HD / 8), col = (c % (HD / 8)) * 8;
            kreg[i] = *(const short8*)(Kb + (size_t)(key0 + row) * D_ + col);
        }
#pragma unroll
        for (int i = 0; i < VC; ++i) {
            int c = tid + i * 512;
            int row = c >> 2, col = (c & 3) * 8;
            vreg[i] = *(const short8*)(Vb + (size_t)row * S_ + key0 + col);
        }
    };

    LOADKV(0);

    for (int t = 0; t < 16; ++t) {
        int key0 = t * 32;
        int p = (NBUF == 2) ? (t & 1) : 0;
        if (NBUF == 1) __syncthreads();   // single-buffer: prior reads must drain
#pragma unroll
        for (int i = 0; i < KC; ++i) {
            int c = tid + i * 512;
            int row = c / (HD / 8), col = (c % (HD / 8)) * 8;
            *(short8*)&Ks[p][row * KP + col] = kreg[i];
        }
#pragma unroll
        for (int i = 0; i < VC; ++i) {
            int c = tid + i * 512;
            int row = c >> 2, col = (c & 3) * 8;
            *(short8*)&Vs[p][row * VP + col] = vreg[i];
        }
        if (key0 + 32 < S_) LOADKV(key0 + 32);   // land during compute below
        int tok0 = xb[key0 + l16] != 0;
        int tok1 = xb[key0 + 16 + l16] != 0;
        __syncthreads();   // staged tile visible to all waves

        f32x4 sc0 = (f32x4){0.f, 0.f, 0.f, 0.f};
        f32x4 sc1 = (f32x4){0.f, 0.f, 0.f, 0.f};
#pragma unroll
        for (int f = 0; f < NKF; ++f) {
            short8 k0 = *(const short8*)&Ks[p][l16 * KP + f * 32 + quad * 8];
            short8 k1 = *(const short8*)&Ks[p][(16 + l16) * KP + f * 32 + quad * 8];
            sc0 = __builtin_amdgcn_mfma_f32_16x16x32_bf16(qf[f], k0, sc0, 0, 0, 0);
            sc1 = __builtin_amdgcn_mfma_f32_16x16x32_bf16(qf[f], k1, sc1, 0, 0, 0);
        }
#pragma unroll
        for (int r = 0; r < 4; ++r) {
            float p0 = tok0 ? __expf(sc0[r] * scale) : 0.f;
            float p1 = tok1 ? __expf(sc1[r] * scale) : 0.f;
            lpart[r] += p0 + p1;
            Pl[wid * 512 + (quad * 4 + r) * 32 + l16] = f2b(p0);
            Pl[wid * 512 + (quad * 4 + r) * 32 + 16 + l16] = f2b(p1);
        }
        __asm volatile("s_waitcnt lgkmcnt(0)" ::: "memory");  // wave-private P: write->read
        short8 pf = *(const short8*)&Pl[wid * 512 + l16 * 32 + quad * 8];
#pragma unroll
        for (int f = 0; f < NOF; ++f) {
            short8 vf = *(const short8*)&Vs[p][(f * 16 + l16) * VP + quad * 8];
            of[f] = __builtin_amdgcn_mfma_f32_16x16x32_bf16(pf, vf, of[f], 0, 0, 0);
        }
    }

    u16* Ob = O + (size_t)(b * S_) * D_ + h * HD;
    float rl[4];
#pragma unroll
    for (int r = 0; r < 4; ++r) {
        float l = lpart[r];
#pragma unroll
        for (int msk = 1; msk < 16; msk <<= 1) l += __shfl_xor(l, msk, 64);
        rl[r] = 1.0f / l;
    }
#pragma unroll
    for (int f = 0; f < NOF; ++f)
#pragma unroll
        for (int r = 0; r < 4; ++r)
            Ob[(size_t)(qrow + quad * 4 + r) * D_ + f * 16 + l16] =
                f2b(of[f][r] * rl[r]);
}

// ---------------- pool stage 0: zero accumulators ----------------
__global__ __launch_bounds__(256) void pool_zero_k(float* __restrict__ pooled) {
    int b = blockIdx.x;
    for (int i = threadIdx.x; i < 1024; i += 256) pooled[b * 1024 + i] = 0.f;
}

// ---------------- pool final: count tokens inline + LayerNorm + linear ----------------
__global__ __launch_bounds__(256) void pool_final_k(
    const float* __restrict__ pooled, const int* __restrict__ x,
    const u16* __restrict__ prm, void* __restrict__ out, const int* __restrict__ flagp)
{
    __shared__ float sb[8];
    __shared__ int sbi[4];
    const u16* g  = prm + 8 * 1024;
    const u16* be = prm + 9 * 1024;
    const u16* lw = prm + 10 * 1024;
    const u16* lb = prm + 11 * 1024;
    int b = blockIdx.x;
    int c = threadIdx.x * 4;
    int wid = threadIdx.x >> 6, lane = threadIdx.x & 63;

    // inline token count (replaces pool_partial's cnt)
    const int* xb = x + b * S_;
    int localc = 0;
    for (int i = threadIdx.x; i < S_; i += 256) localc += (xb[i] != 0);
#pragma unroll
    for (int m = 32; m >= 1; m >>= 1) localc += __shfl_xor(localc, m, 64);
    if (lane == 0) sbi[wid] = localc;
    __syncthreads();
    int n = sbi[0] + sbi[1] + sbi[2] + sbi[3];

    float inv = 1.0f / (float)(n > 0 ? n : 1);
    float p0 = pooled[b * 1024 + c + 0] * inv;
    float p1 = pooled[b * 1024 + c + 1] * inv;
    float p2 = pooled[b * 1024 + c + 2] * inv;
    float p3 = pooled[b * 1024 + c + 3] * inv;
    float s1 = p0 + p1 + p2 + p3;
    float s2 = p0 * p0 + p1 * p1 + p2 * p2 + p3 * p3;
#pragma unroll
    for (int m = 32; m >= 1; m >>= 1) { s1 += __shfl_xor(s1, m, 64); s2 += __shfl_xor(s2, m, 64); }
    if (lane == 0) { sb[wid] = s1; sb[4 + wid] = s2; }
    __syncthreads();
    float S1 = sb[0] + sb[1] + sb[2] + sb[3];
    float S2 = sb[4] + sb[5] + sb[6] + sb[7];
    float mu = S1 * (1.0f / 1024.0f);
    float var = S2 * (1.0f / 1024.0f) - mu * mu;
    float rstd = rsqrtf(var + 1e-5f);
    float dot = ((p0 - mu) * rstd * b2f(g[c + 0]) + b2f(be[c + 0])) * b2f(lw[c + 0])
              + ((p1 - mu) * rstd * b2f(g[c + 1]) + b2f(be[c + 1])) * b2f(lw[c + 1])
              + ((p2 - mu) * rstd * b2f(g[c + 2]) + b2f(be[c + 2])) * b2f(lw[c + 2])
              + ((p3 - mu) * rstd * b2f(g[c + 3]) + b2f(be[c + 3])) * b2f(lw[c + 3]);
#pragma unroll
    for (int m = 32; m >= 1; m >>= 1) dot += __shfl_xor(dot, m, 64);
    __syncthreads();
    if (lane == 0) sb[wid] = dot;
    __syncthreads();
    if (threadIdx.x == 0) {
        float v = sb[0] + sb[1] + sb[2] + sb[3] + b2f(lb[0]);
        if (*flagp) ((u16*)out)[b] = f2b(v);
        else        ((float*)out)[b] = v;
    }
}

extern "C" void kernel_launch(void* const* d_in, const int* in_sizes, int n_in,
                              void* d_out, int out_size, void* d_ws, size_t ws_size,
                              hipStream_t stream)
{
    (void)in_sizes; (void)n_in; (void)out_size; (void)ws_size;
    const int* x = (const int*)d_in[0];

    char* ws = (char*)d_ws;
    size_t off = 0;
    auto carve = [&](size_t bytes) -> char* {
        char* p = ws + off;
        off += (bytes + 255) & ~(size_t)255;
        return p;
    };
    int* flag    = (int*)carve(256);
    u16* prm     = (u16*)carve(12 * 1024 * 2);
    float* pooled = (float*)carve(64 * 1024 * 4);
    int* cnt     = (int*)carve(64 * 4);
    (void)cnt;
    const size_t WB = (size_t)D_ * D_ * 2;   // 2 MiB (multiple of 256 -> wt[i] contiguous)
    const size_t HB = (size_t)BS_ * D_ * 2;  // 64 MiB
    u16* wt0 = (u16*)carve(WB * 8);          // 8 transposed weights, contiguous
    u16* h0   = (u16*)carve(HB);
    u16* buf2 = (u16*)carve(HB);
    u16* buf3 = (u16*)carve(HB);
    u16* buf4 = (u16*)carve(HB);
    u16* buf5 = (u16*)carve(HB);
    const size_t WE = (size_t)D_ * D_;       // elements per weight

    detect_k<<<1, 256, 0, stream>>>((const u16*)d_in[1], flag);
    convert_params_k<<<12, 256, 0, stream>>>(
        d_in[4], d_in[6], d_in[8], d_in[10], d_in[12], d_in[14], d_in[16], d_in[18],
        d_in[19], d_in[20], d_in[21], d_in[22], flag, prm);

    // all 8 weight transposes in ONE dispatch (8192 blocks fills the machine once)
    transpose_all_k<<<dim3(32, 32, 8), dim3(32, 8), 0, stream>>>(
        d_in[3], d_in[5], d_in[7], d_in[9], d_in[11], d_in[13], d_in[15], d_in[17],
        wt0, flag);

    embed_k<<<BS_, 256, 0, stream>>>(x, d_in[1], d_in[2], h0, flag);

    // zero pooled early (independent of the main chain)
    pool_zero_k<<<B_, 256, 0, stream>>>(pooled);

    // MHA1: fused QKV (Bt = wt[0..2] contiguous, bias = prm slots 0..2)
    gemm256_k<12><<<1536, 512, 0, stream>>>(h0, wt0 + 0 * WE, prm + 0 * 1024,
                                            nullptr, nullptr, buf2, buf3, buf4,
                                            nullptr, nullptr);
    attn8_k<128, 2><<<dim3(B_ * 8, 4), 512, 0, stream>>>(buf2, buf3, buf4, x, buf2, 8);
    gemm256_k<4><<<512, 512, 0, stream>>>(buf2, wt0 + 3 * WE, prm + 3 * 1024,
                                          h0, nullptr, buf5, nullptr, nullptr,
                                          nullptr, nullptr);
    // MHA2: fused QKV (Bt = wt[4..6] contiguous, bias = prm slots 4..6)
    gemm256_k<12><<<1536, 512, 0, stream>>>(buf5, wt0 + 4 * WE, prm + 4 * 1024,
                                            nullptr, nullptr, buf2, buf3, buf4,
                                            nullptr, nullptr);
    attn8_k<256, 2><<<dim3(B_ * 4, 4), 512, 0, stream>>>(buf2, buf3, buf4, x, buf2, 4);
    // final proj: fuses residuals AND the masked mean-pool accumulation
    gemm256_k<4><<<512, 512, 0, stream>>>(buf2, wt0 + 7 * WE, prm + 7 * 1024,
                                          buf5, h0, nullptr, nullptr, nullptr,
                                          x, pooled);

    pool_final_k<<<B_, 256, 0, stream>>>(pooled, x, prm, d_out, flag);
}